// Round 1
// baseline (735.178 us; speedup 1.0000x reference)
//
#include <hip/hip_runtime.h>

#define L_DIM 30000
#define NT 512
#define NWAVE (NT / 64)
#define VEC 4
#define STRIDE (NT * VEC)          // 2048 elements per block iteration
#define FULL_ITERS 14              // iterations guaranteed fully in-range
#define ITERS 15                   // ceil(30000 / 2048)
#define HGROUPS 4                  // privatized histogram copies
#define MVAL 50
#define EPS_F 1e-8f
#define ALPHA_F 0.8f

// ---- bf16 bit helpers (RNE) ----
__device__ __forceinline__ unsigned short f2bf(float f) {
    unsigned int u = __float_as_uint(f);
    unsigned int r = (u + 0x7FFFu + ((u >> 16) & 1u)) >> 16;
    return (unsigned short)r;
}
__device__ __forceinline__ float bf2f(unsigned short h) {
    return __uint_as_float(((unsigned int)h) << 16);
}

struct __align__(16) Smem {
    unsigned short buf[L_DIM];           // 60000 B: bf16 logits, then bf16 bce (in place)
    unsigned int hist[HGROUPS][257];     // 4112 B: padded (257) so groups hit different banks
    float redA[NWAVE];
    float redB[NWAVE];
    float rm, sn;
    unsigned int sel[4];
};

__device__ __forceinline__ void p1body(const float4 lv, const int4 tv, int it, int j,
                                       unsigned short* buf, float& m, float& s,
                                       unsigned long long& bits) {
    ushort4 h;
    h.x = f2bf(lv.x); h.y = f2bf(lv.y); h.z = f2bf(lv.z); h.w = f2bf(lv.w);
    *reinterpret_cast<ushort4*>(&buf[j]) = h;   // 8 B aligned store
    float xs[4] = {lv.x, lv.y, lv.z, lv.w};
    int   tt[4] = {tv.x, tv.y, tv.z, tv.w};
#pragma unroll
    for (int e = 0; e < 4; ++e) {
        float x = xs[e];
        if (tt[e]) bits |= (1ull << (it * 4 + e));
        if (x > m) { s *= __expf(m - x); m = x; }   // online max rescale (rare)
        if (!tt[e]) s += __expf(x - m);             // negatives only
    }
}

extern "C" __global__ __launch_bounds__(NT, 4)
void ctn_main(const float* __restrict__ logits, const int* __restrict__ targets,
              double* __restrict__ acc) {
    __shared__ Smem sm;
    const int tid  = threadIdx.x;
    const int wid  = tid >> 6;
    const int lane = tid & 63;
    const size_t rowoff = (size_t)blockIdx.x * L_DIM;
    const float* Lr = logits + rowoff;
    const int*   Tr = targets + rowoff;

    // ---------- Pass 1: stream from HBM once ----------
    float m = -INFINITY, s = 0.0f;
    unsigned long long bits = 0ull;
#pragma unroll 4
    for (int it = 0; it < FULL_ITERS; ++it) {
        int j = it * STRIDE + tid * VEC;
        float4 lv = *reinterpret_cast<const float4*>(Lr + j);
        int4   tv = *reinterpret_cast<const int4*>(Tr + j);
        p1body(lv, tv, it, j, sm.buf, m, s, bits);
    }
    {
        int j = FULL_ITERS * STRIDE + tid * VEC;
        if (j < L_DIM) {
            float4 lv = *reinterpret_cast<const float4*>(Lr + j);
            int4   tv = *reinterpret_cast<const int4*>(Tr + j);
            p1body(lv, tv, FULL_ITERS, j, sm.buf, m, s, bits);
        }
    }

    // ---------- block reduce (max, neg-exp-sum) ----------
#pragma unroll
    for (int off = 32; off > 0; off >>= 1) {
        float om = __shfl_down(m, off), os = __shfl_down(s, off);
        float nm = fmaxf(m, om);
        s = s * __expf(m - nm) + os * __expf(om - nm);
        m = nm;
    }
    if (lane == 0) { sm.redA[wid] = m; sm.redB[wid] = s; }
    __syncthreads();
    if (wid == 0) {
        float mm = (lane < NWAVE) ? sm.redA[lane] : -INFINITY;
        float ss = (lane < NWAVE) ? sm.redB[lane] : 0.0f;
#pragma unroll
        for (int off = NWAVE / 2; off > 0; off >>= 1) {
            float om = __shfl_down(mm, off), os = __shfl_down(ss, off);
            float nm = fmaxf(mm, om);
            ss = ss * __expf(mm - nm) + os * __expf(om - nm);
            mm = nm;
        }
        if (lane == 0) { sm.rm = mm; sm.sn = ss; }
    }
    __syncthreads();
    const float rm = sm.rm, sneg = sm.sn;

    // ---------- Pass 2: CE positives + BCE (in-place bf16) ----------
    float ce = 0.0f, np = 0.0f;
#pragma unroll
    for (int it = 0; it < ITERS; ++it) {
        int j = it * STRIDE + tid * VEC;
        bool ok = (it < FULL_ITERS) || (j < L_DIM);
        if (ok) {
            ushort4 h = *reinterpret_cast<ushort4*>(&sm.buf[j]);
            unsigned short hv[4] = {h.x, h.y, h.z, h.w};
            unsigned short ov[4];
#pragma unroll
            for (int e = 0; e < 4; ++e) {
                float x = bf2f(hv[e]);
                bool pos = (bits >> (it * 4 + e)) & 1ull;
                if (pos) {
                    ce += rm + __logf(__expf(x - rm) + sneg) - x;
                    np += 1.0f;
                }
                float en = __expf(-x);
                float p  = 1.0f / (1.0f + en);
                float q  = pos ? (p + EPS_F) : (1.0f - p + EPS_F);
                float bce = fmaxf(-__logf(q), 0.0f);
                ov[e] = f2bf(bce);
            }
            ushort4 o; o.x = ov[0]; o.y = ov[1]; o.z = ov[2]; o.w = ov[3];
            *reinterpret_cast<ushort4*>(&sm.buf[j]) = o;
        }
    }
#pragma unroll
    for (int off = 32; off > 0; off >>= 1) {
        ce += __shfl_down(ce, off);
        np += __shfl_down(np, off);
    }
    if (lane == 0) { sm.redA[wid] = ce; sm.redB[wid] = np; }
    __syncthreads();
    if (tid == 0) {
        float cet = 0.0f, npt = 0.0f;
#pragma unroll
        for (int g = 0; g < NWAVE; ++g) { cet += sm.redA[g]; npt += sm.redB[g]; }
        atomicAdd(&acc[0], (double)cet);
        atomicAdd(&acc[2], (double)npt);
    }
    __syncthreads();   // buf fully written + redA/redB free for reuse

    // ---------- Pass 3: radix-select top-50 of bf16 bce keys ----------
    for (int i = tid; i < HGROUPS * 257; i += NT) (&sm.hist[0][0])[i] = 0u;
    __syncthreads();
    const int g = wid & (HGROUPS - 1);
    const ushort4* b4 = reinterpret_cast<const ushort4*>(sm.buf);
    for (int i = tid; i < L_DIM / 4; i += NT) {
        ushort4 v = b4[i];
        atomicAdd(&sm.hist[g][v.x >> 8], 1u);
        atomicAdd(&sm.hist[g][v.y >> 8], 1u);
        atomicAdd(&sm.hist[g][v.z >> 8], 1u);
        atomicAdd(&sm.hist[g][v.w >> 8], 1u);
    }
    __syncthreads();
    if (tid < 256) {
        unsigned int c = 0;
#pragma unroll
        for (int gg = 0; gg < HGROUPS; ++gg) c += sm.hist[gg][tid];
        sm.hist[0][tid] = c;
    }
    __syncthreads();
    if (tid == 0) {
        unsigned int cum = 0; int bs = 0;
        for (int b = 255; b >= 0; --b) {
            unsigned int c = sm.hist[0][b];
            if (cum + c >= MVAL) { bs = b; break; }
            cum += c;
        }
        sm.sel[0] = (unsigned int)bs; sm.sel[1] = cum;
    }
    __syncthreads();
    const unsigned int bstar = sm.sel[0], above_hi = sm.sel[1];
    if (tid < 256) sm.hist[1][tid] = 0u;
    __syncthreads();
    for (int i = tid; i < L_DIM / 4; i += NT) {
        ushort4 v = b4[i];
        unsigned short vv[4] = {v.x, v.y, v.z, v.w};
#pragma unroll
        for (int e = 0; e < 4; ++e)
            if ((unsigned int)(vv[e] >> 8) == bstar)
                atomicAdd(&sm.hist[1][vv[e] & 255], 1u);
    }
    __syncthreads();
    if (tid == 0) {
        unsigned int cum = above_hi;
        unsigned int key = (bstar << 8);
        for (int b = 255; b >= 0; --b) {
            unsigned int c = sm.hist[1][b];
            if (cum + c >= MVAL) { sm.sel[2] = key | (unsigned int)b; sm.sel[3] = cum; break; }
            cum += c;
        }
    }
    __syncthreads();
    const unsigned int tkey = sm.sel[2], above = sm.sel[3];
    float sum = 0.0f;
    for (int i = tid; i < L_DIM / 4; i += NT) {
        ushort4 v = b4[i];
        unsigned short vv[4] = {v.x, v.y, v.z, v.w};
#pragma unroll
        for (int e = 0; e < 4; ++e)
            if ((unsigned int)vv[e] > tkey) sum += bf2f(vv[e]);
    }
#pragma unroll
    for (int off = 32; off > 0; off >>= 1) sum += __shfl_down(sum, off);
    if (lane == 0) sm.redA[wid] = sum;
    __syncthreads();
    if (tid == 0) {
        float st = 0.0f;
#pragma unroll
        for (int gg = 0; gg < NWAVE; ++gg) st += sm.redA[gg];
        float tval = bf2f((unsigned short)tkey);
        float rmean = (st + (float)(MVAL - (int)above) * tval) * (1.0f / (float)MVAL);
        atomicAdd(&acc[1], (double)rmean);
    }
}

extern "C" __global__ void ctn_final(const double* __restrict__ acc,
                                     float* __restrict__ out, int rows) {
    double ce_sum = acc[0], mb_sum = acc[1], npos = acc[2];
    float ce   = (npos > 0.0) ? (float)(ce_sum / npos) : 0.0f;
    float mbce = (float)(mb_sum / (double)rows);
    out[0] = ALPHA_F * ce + (1.0f - ALPHA_F) * mbce;
    out[1] = ce;
    out[2] = mbce;
}

extern "C" void kernel_launch(void* const* d_in, const int* in_sizes, int n_in,
                              void* d_out, int out_size, void* d_ws, size_t ws_size,
                              hipStream_t stream) {
    const float* logits  = (const float*)d_in[0];
    const int*   targets = (const int*)d_in[1];
    float*  out = (float*)d_out;
    double* acc = (double*)d_ws;
    int rows = in_sizes[0] / L_DIM;   // 2048

    hipMemsetAsync(d_ws, 0, 3 * sizeof(double), stream);
    hipLaunchKernelGGL(ctn_main, dim3(rows), dim3(NT), 0, stream,
                       logits, targets, acc);
    hipLaunchKernelGGL(ctn_final, dim3(1), dim3(1), 0, stream, acc, out, rows);
}

// Round 3
// 503.182 us; speedup vs baseline: 1.4611x; 1.4611x over previous
//
#include <hip/hip_runtime.h>

#define L_DIM 30000
#define NT 512
#define NWAVE 8
#define VEC 4
#define STRIDE (NT * VEC)          // 2048 elements per iteration
#define FULL_ITERS 14
#define CAP 4096
#define HG 4
#define MVAL 50
#define ALPHA_F 0.8f
#define K0 0x4000u                 // bf16(2.0) prefilter floor

// ---- bf16 bit helpers (RNE) ----
__device__ __forceinline__ unsigned short f2bf(float f) {
    unsigned int u = __float_as_uint(f);
    unsigned int r = (u + 0x7FFFu + ((u >> 16) & 1u)) >> 16;
    return (unsigned short)r;
}
__device__ __forceinline__ float bf2f(unsigned short h) {
    return __uint_as_float(((unsigned int)h) << 16);
}

struct __align__(16) Smem {
    unsigned short cb[CAP];          // 8 KB compacted candidate keys
    unsigned int hist[HG][257];      // 4.1 KB privatized histograms
    float red[NWAVE][8];
    unsigned int part[4];
    unsigned int ccount;
    unsigned int sel[4];
};

// recompute key from global (slow fallback path only)
__device__ __forceinline__ unsigned slowkey(const float* Lr, const int* Tr, int i) {
    float x = Lr[i];
    int t = Tr[i];
    float en = __expf(-x);
    float l1p = __logf(1.0f + en);
    float bce = (t ? 0.0f : x) + l1p;
    return (unsigned)f2bf(fmaxf(bce, 0.0f));
}

extern "C" __global__ __launch_bounds__(NT, 8)
void ctn_main(const float* __restrict__ logits, const int* __restrict__ targets,
              double* __restrict__ acc) {
    __shared__ Smem sm;
    const int tid  = threadIdx.x;
    const int wid  = tid >> 6;
    const int lane = tid & 63;
    const unsigned long long lt = (1ull << lane) - 1ull;
    const size_t rowoff = (size_t)blockIdx.x * L_DIM;
    const float* Lr = logits + rowoff;
    const int*   Tr = targets + rowoff;

    if (tid == 0) sm.ccount = 0u;
    __syncthreads();

    // ---------- single streaming pass ----------
    float sall = 0.f, P1 = 0.f, P2 = 0.f, P3 = 0.f, sx = 0.f, np = 0.f;

    for (int it = 0; it <= FULL_ITERS; ++it) {
        int j = it * STRIDE + tid * VEC;
        bool ok = (it < FULL_ITERS) || (j < L_DIM);
        float4 lv = make_float4(0.f, 0.f, 0.f, 0.f);
        int4   tv = make_int4(0, 0, 0, 0);
        if (ok) {
            lv = *reinterpret_cast<const float4*>(Lr + j);
            tv = *reinterpret_cast<const int4*>(Tr + j);
        }
        float xs[4] = {lv.x, lv.y, lv.z, lv.w};
        int   ts[4] = {tv.x, tv.y, tv.z, tv.w};
        unsigned short kk[4];
        bool hi[4];
#pragma unroll
        for (int e = 0; e < 4; ++e) { kk[e] = 0; hi[e] = false; }
        if (ok) {
#pragma unroll
            for (int e = 0; e < 4; ++e) {
                float x = xs[e];
                bool pos = ts[e] != 0;
                float eo = __expf(x);
                sall += eo;                       // S_neg = sall - P1 later
                float epos = pos ? eo : 0.0f;
                P1 += epos;
                float t1 = epos * eo;
                P2 += t1;
                P3 = fmaf(t1, eo, P3);
                sx += pos ? x : 0.0f;
                np += pos ? 1.0f : 0.0f;
                float en  = __expf(-x);
                float l1p = __logf(1.0f + en);
                float bce = (pos ? 0.0f : x) + l1p;   // softplus identity
                unsigned short kv = f2bf(fmaxf(bce, 0.0f));
                kk[e] = kv;
                hi[e] = (unsigned)kv >= K0;
            }
        }
        // ballot compaction: one LDS atomic per wave-iteration
        unsigned long long m0 = __ballot(hi[0]);
        unsigned long long m1 = __ballot(hi[1]);
        unsigned long long m2 = __ballot(hi[2]);
        unsigned long long m3 = __ballot(hi[3]);
        unsigned tot = (unsigned)(__popcll(m0) + __popcll(m1) +
                                  __popcll(m2) + __popcll(m3));
        unsigned base = 0u;
        if (lane == 0 && tot) base = atomicAdd(&sm.ccount, tot);
        base = __shfl(base, 0);
        unsigned n0 = (unsigned)__popcll(m0);
        unsigned n1 = (unsigned)__popcll(m1);
        unsigned n2 = (unsigned)__popcll(m2);
        unsigned o0 = base + (unsigned)__popcll(m0 & lt);
        unsigned o1 = base + n0 + (unsigned)__popcll(m1 & lt);
        unsigned o2 = base + n0 + n1 + (unsigned)__popcll(m2 & lt);
        unsigned o3 = base + n0 + n1 + n2 + (unsigned)__popcll(m3 & lt);
        if (hi[0] && o0 < CAP) sm.cb[o0] = kk[0];
        if (hi[1] && o1 < CAP) sm.cb[o1] = kk[1];
        if (hi[2] && o2 < CAP) sm.cb[o2] = kk[2];
        if (hi[3] && o3 < CAP) sm.cb[o3] = kk[3];
    }

    // ---------- row reduction + CE series ----------
#pragma unroll
    for (int off = 32; off > 0; off >>= 1) {
        sall += __shfl_down(sall, off);
        P1   += __shfl_down(P1, off);
        P2   += __shfl_down(P2, off);
        P3   += __shfl_down(P3, off);
        sx   += __shfl_down(sx, off);
        np   += __shfl_down(np, off);
    }
    if (lane == 0) {
        sm.red[wid][0] = sall; sm.red[wid][1] = P1; sm.red[wid][2] = P2;
        sm.red[wid][3] = P3;   sm.red[wid][4] = sx; sm.red[wid][5] = np;
    }
    __syncthreads();
    if (tid == 0) {
        double tS = 0, tP1 = 0, tP2 = 0, tP3 = 0, tsx = 0, tnp = 0;
        for (int w = 0; w < NWAVE; ++w) {
            tS  += sm.red[w][0]; tP1 += sm.red[w][1]; tP2 += sm.red[w][2];
            tP3 += sm.red[w][3]; tsx += sm.red[w][4]; tnp += sm.red[w][5];
        }
        double S = tS - tP1;                     // sum exp over negatives
        if (tnp > 0.0) {
            atomicAdd(&acc[2], tnp);
            if (S > 0.0) {
                // sum_pos log(S+e^x)-x = np*logS + P1/S - P2/2S^2 + P3/3S^3 - sx
                double ce_row = tnp * log(S) + tP1 / S - 0.5 * tP2 / (S * S)
                              + tP3 / (3.0 * S * S * S) - tsx;
                atomicAdd(&acc[0], ce_row);
            }
        }
    }
    __syncthreads();

    // ---------- top-50 select on compacted candidates ----------
    unsigned cc = sm.ccount;
    bool fast = (cc >= (unsigned)MVAL) && (cc <= (unsigned)CAP);
    int nitems = fast ? (int)cc : L_DIM;

    unsigned int* hflat = &sm.hist[0][0];
    for (int i = tid; i < HG * 257; i += NT) hflat[i] = 0u;
    __syncthreads();
    const int g = wid & (HG - 1);
    for (int i = tid; i < nitems; i += NT) {
        unsigned k = fast ? (unsigned)sm.cb[i] : slowkey(Lr, Tr, i);
        atomicAdd(&sm.hist[g][k >> 8], 1u);
    }
    __syncthreads();

    // level-1: parallel suffix scan over 256 high-byte bins
    unsigned c1 = 0, p1 = 0; int bin1 = 0;
    if (tid < 256) {
        bin1 = 255 - tid;
        c1 = sm.hist[0][bin1] + sm.hist[1][bin1] + sm.hist[2][bin1] + sm.hist[3][bin1];
    }
    p1 = c1;
#pragma unroll
    for (int off = 1; off < 64; off <<= 1) {
        unsigned o = __shfl_up(p1, off);
        if (lane >= off) p1 += o;
    }
    if (tid < 256 && lane == 63) sm.part[wid] = p1;
    __syncthreads();
    if (tid < 256) {
        unsigned addv = 0;
        for (int gg = 0; gg < wid; ++gg) addv += sm.part[gg];
        unsigned R = p1 + addv;                  // count of keys with highbyte >= bin1
        if (R >= (unsigned)MVAL && (R - c1) < (unsigned)MVAL) {
            sm.sel[0] = (unsigned)bin1;
            sm.sel[1] = R - c1;                  // strictly above threshold bin
        }
    }
    __syncthreads();
    const unsigned bstar = sm.sel[0], above_hi = sm.sel[1];

    // level-2: low byte within threshold bin
    for (int i = tid; i < HG * 257; i += NT) hflat[i] = 0u;
    __syncthreads();
    for (int i = tid; i < nitems; i += NT) {
        unsigned k = fast ? (unsigned)sm.cb[i] : slowkey(Lr, Tr, i);
        if ((k >> 8) == bstar) atomicAdd(&sm.hist[g][k & 255u], 1u);
    }
    __syncthreads();
    unsigned c2 = 0, p2 = 0; int bin2 = 0;
    if (tid < 256) {
        bin2 = 255 - tid;
        c2 = sm.hist[0][bin2] + sm.hist[1][bin2] + sm.hist[2][bin2] + sm.hist[3][bin2];
    }
    p2 = c2;
#pragma unroll
    for (int off = 1; off < 64; off <<= 1) {
        unsigned o = __shfl_up(p2, off);
        if (lane >= off) p2 += o;
    }
    if (tid < 256 && lane == 63) sm.part[wid] = p2;
    __syncthreads();
    if (tid < 256) {
        unsigned addv = 0;
        for (int gg = 0; gg < wid; ++gg) addv += sm.part[gg];
        unsigned R2 = above_hi + p2 + addv;
        if (R2 >= (unsigned)MVAL && (R2 - c2) < (unsigned)MVAL) {
            sm.sel[2] = (bstar << 8) | (unsigned)bin2;   // exact bf16 threshold key
            sm.sel[3] = R2 - c2;                         // strictly above tkey
        }
    }
    __syncthreads();
    const unsigned tkey = sm.sel[2], above = sm.sel[3];

    // sum strictly-above + tie fill
    float ssum = 0.0f;
    for (int i = tid; i < nitems; i += NT) {
        unsigned k = fast ? (unsigned)sm.cb[i] : slowkey(Lr, Tr, i);
        if (k > tkey) ssum += bf2f((unsigned short)k);
    }
#pragma unroll
    for (int off = 32; off > 0; off >>= 1) ssum += __shfl_down(ssum, off);
    if (lane == 0) sm.red[wid][0] = ssum;
    __syncthreads();
    if (tid == 0) {
        double st = 0.0;
        for (int w = 0; w < NWAVE; ++w) st += (double)sm.red[w][0];
        double tval = (double)bf2f((unsigned short)tkey);
        double rmean = (st + (double)(MVAL - (int)above) * tval) / (double)MVAL;
        atomicAdd(&acc[1], rmean);
    }
}

extern "C" __global__ void ctn_final(const double* __restrict__ acc,
                                     float* __restrict__ out, int rows) {
    double ce_sum = acc[0], mb_sum = acc[1], npos = acc[2];
    float ce   = (npos > 0.0) ? (float)(ce_sum / npos) : 0.0f;
    float mbce = (float)(mb_sum / (double)rows);
    out[0] = ALPHA_F * ce + (1.0f - ALPHA_F) * mbce;
    out[1] = ce;
    out[2] = mbce;
}

extern "C" void kernel_launch(void* const* d_in, const int* in_sizes, int n_in,
                              void* d_out, int out_size, void* d_ws, size_t ws_size,
                              hipStream_t stream) {
    const float* logits  = (const float*)d_in[0];
    const int*   targets = (const int*)d_in[1];
    float*  out = (float*)d_out;
    double* acc = (double*)d_ws;
    int rows = in_sizes[0] / L_DIM;   // 2048

    hipMemsetAsync(d_ws, 0, 3 * sizeof(double), stream);
    hipLaunchKernelGGL(ctn_main, dim3(rows), dim3(NT), 0, stream,
                       logits, targets, acc);
    hipLaunchKernelGGL(ctn_final, dim3(1), dim3(1), 0, stream, acc, out, rows);
}